// Round 12
// baseline (214.654 us; speedup 1.0000x reference)
//
#include <hip/hip_runtime.h>
#include <hip/hip_bf16.h>

typedef __hip_bfloat16 bf16;
typedef unsigned short ushort;
typedef unsigned int uint;
typedef __attribute__((ext_vector_type(8))) short short8;
typedef __attribute__((ext_vector_type(4))) float f32x4;

#define Bsz 2
#define Tn  1536
#define Cn  1536
#define Hn  8
#define Kn  64
#define Vn  192
// H*K = 512, H*V = 1536, 2T-1 = 3071

__device__ __forceinline__ ushort f2bs(float f) {
  union { bf16 h; ushort u; } cv;
  cv.h = __float2bfloat16(f);
  return cv.u;
}
__device__ __forceinline__ float bs2f(ushort u) {
  union { float f; uint v; } cv; cv.v = ((uint)u) << 16; return cv.f;
}

// async global->LDS, 16B per lane; LDS dest = wave-uniform base + lane*16
__device__ __forceinline__ void gld_lds16(const ushort* g, ushort* l) {
  __builtin_amdgcn_global_load_lds(
      (const __attribute__((address_space(1))) uint*)g,
      (__attribute__((address_space(3))) uint*)l, 16, 0, 0);
}

// 16-lane max-reduce step via DPP (VALU-rate, no LDS): x = max(x, dpp(x))
#define DPP_MAXSTEP(x, ctrl)                                                  \
  do {                                                                        \
    union { float f; int i; } a_, b_;                                         \
    a_.f = (x);                                                               \
    b_.i = __builtin_amdgcn_update_dpp(a_.i, a_.i, (ctrl), 0xf, 0xf, true);   \
    (x) = fmaxf((x), b_.f);                                                   \
  } while (0)

// ---------------------------------------------------------------------------
// Merged prep kernel, grid (48,48,6):
//  z=0..3: transpose+cvt  W{q,k,v,o} f32 [1536][Cc] -> bf16 [Cc][1536]
//  z=4   : x f32 -> xb bf16 (vectorized x4, grid-stride)
//  z=5   : rkd[8][40][64] bf16 (33 DISTINCT rel-basis rows per head; rows
//          33..39 ZERO pad) and lutb[3072] u8: d+1535 -> row index u.
// ---------------------------------------------------------------------------
__global__ __launch_bounds__(256) void prep(
    const float* __restrict__ x,  const float* __restrict__ Wq,
    const float* __restrict__ Wk, const float* __restrict__ Wv,
    const float* __restrict__ Wo, const float* __restrict__ Wr,
    ushort* __restrict__ xb, ushort* __restrict__ Wt,
    ushort* __restrict__ Wot, ushort* __restrict__ rkdb,
    unsigned char* __restrict__ lutb) {
  const int z = blockIdx.z;
  if (z < 4) {
    if (z < 2 && blockIdx.x >= 16) return;
    const float* in = (z == 0) ? Wq : (z == 1) ? Wk : (z == 2) ? Wv : Wo;
    ushort* out = (z == 0) ? Wt : (z == 1) ? Wt + 512 * 1536
                : (z == 2) ? Wt + 1024 * 1536 : Wot;
    const int Cc = (z < 2) ? 512 : 1536;
    __shared__ float tile[32][33];
    const int bx = blockIdx.x * 32;
    const int by = blockIdx.y * 32;
    const int tx = threadIdx.x & 31, ty = threadIdx.x >> 5;
#pragma unroll
    for (int i = 0; i < 32; i += 8)
      tile[ty + i][tx] = in[(size_t)(by + ty + i) * Cc + bx + tx];
    __syncthreads();
#pragma unroll
    for (int i = 0; i < 32; i += 8)
      out[(size_t)(bx + ty + i) * 1536 + by + tx] = f2bs(tile[tx][ty + i]);
  } else if (z == 4) {
    const int n4 = 3072 * 1536 / 4;
    for (int i = (blockIdx.y * 48 + blockIdx.x) * 256 + threadIdx.x; i < n4;
         i += 2304 * 256) {
      float4 v = ((const float4*)x)[i];
      uint2 o;
      o.x = (uint)f2bs(v.x) | ((uint)f2bs(v.y) << 16);
      o.y = (uint)f2bs(v.z) | ((uint)f2bs(v.w) << 16);
      ((uint2*)xb)[i] = o;
    }
  } else {
    const int base = (blockIdx.y * 48 + blockIdx.x) * 256 + threadIdx.x;
    if (base < 8 * 40 * 64) {
      // rkd entry: h, u-row (pad 33..39 = 0), k
      const int h = base / 2560, rem = base % 2560, u = rem >> 6, k = rem & 63;
      float acc = 0.f;
      if (u < 33) {
        const float sg = (u == 32) ? 0.f : (u < 16 ? 1.f : -1.f);
        const int c = (u == 32) ? 16 : (u < 16 ? u + 1 : u - 15);
        // active features are the c LARGEST widths: i = 16-c .. 15 (ascending,
        // same summation order as the original rkb builder)
#pragma unroll
        for (int i = 0; i < 16; i++)
          if (i >= 16 - c)
            acc += Wr[i * 512 + h * 64 + k] + sg * Wr[(16 + i) * 512 + h * 64 + k];
      }
      rkdb[h * 2560 + u * 64 + k] = f2bs(acc);
    } else if (base < 8 * 40 * 64 + 3072) {
      const int idx = base - 8 * 40 * 64;       // 0..3071 (3071 = pad)
      const int d = idx - 1535;
      const float ad = fabsf((float)d);
      int c = 0;
#pragma unroll
      for (int i = 0; i < 16; i++) {
        double cw = exp(log((double)(Tn + 1)) * (double)(i + 1) / 16.0) - 1.0;
        if ((float)cw > ad) c++;
      }
      lutb[idx] = (unsigned char)((d == 0) ? 32 : (d > 0 ? c - 1 : 15 + c));
    }
  }
}

// ---------------------------------------------------------------------------
// v9 GEMM core: 128x128 tile, BK=64, DOUBLE-BUFFERED LDS (T3-minimum 2-phase:
// issue next-tile DMA -> compute current -> one barrier/iter; drain covered).
// 128B rows would be a 16-way ds_read conflict -> attn-style XOR swizzle (T2):
// global 16B chunk c of row r staged at physical chunk c^(r&7); ds_read col
// chunk (quad+4ks)^(ln&7). LDS 64KB (2 blocks/CU cap; grids are ~1-2/CU).
// STAGE64: one [128r x 64k] bf16 tile = 16 chunks of 1KB; 4 per wave.
// ---------------------------------------------------------------------------
#define STAGE64(src, base_row, kk, dst)                                       \
  _Pragma("unroll")                                                           \
  for (int i_ = 0; i_ < 4; i_++) {                                            \
    int kc_ = w * 4 + i_, sr_ = kc_ * 8 + lr;                                 \
    gld_lds16(src + (size_t)(base_row + sr_) * 1536 + (kk) + lcx * 8,         \
              dst + kc_ * 512 + lane * 8);                                    \
  }

// ---------------------------------------------------------------------------
// Fused QKV MFMA GEMM: xb @ Wt^T-layout -> qb/kb/vtb.
// XCD-chunked block swizzle (grid 480 = 8 x 60).
// ---------------------------------------------------------------------------
__global__ __launch_bounds__(256) void gemm_qkv(
    const ushort* __restrict__ xb, const ushort* __restrict__ Wt,
    ushort* __restrict__ qb, ushort* __restrict__ kb, ushort* __restrict__ vtb) {
  __shared__ ushort Al[2][128 * 64];
  __shared__ ushort Bl[2][128 * 64];
  const int tid = threadIdx.x;
  const int w = tid >> 6, lane = tid & 63, quad = lane >> 4, ln = lane & 15;
  const int lr = lane >> 3, lcx = (lane & 7) ^ lr;
  const int Lb = blockIdx.x + 20 * blockIdx.y;          // 0..479
  const int wg = (Lb & 7) * 60 + (Lb >> 3);             // bijective (480%8==0)
  const int bm = (wg % 24) * 128, bn = (wg / 24) * 128;
  const int wm = (w & 1) * 64, wn = (w >> 1) * 64;
  f32x4 acc[4][4];
#pragma unroll
  for (int i = 0; i < 4; i++)
#pragma unroll
    for (int j = 0; j < 4; j++) acc[i][j] = (f32x4){0.f, 0.f, 0.f, 0.f};

  STAGE64(xb, bm, 0, Al[0]);
  STAGE64(Wt, bn, 0, Bl[0]);
  __syncthreads();

  int cur = 0;
  for (int k0 = 0; k0 < 1536; k0 += 64) {
    if (k0 + 64 < 1536) {
      STAGE64(xb, bm, k0 + 64, Al[cur ^ 1]);
      STAGE64(Wt, bn, k0 + 64, Bl[cur ^ 1]);
    }
#pragma unroll
    for (int ks = 0; ks < 2; ks++) {
      short8 af[4], bfr[4];
#pragma unroll
      for (int t = 0; t < 4; t++) {
        int cx = ((quad + 4 * ks) ^ (ln & 7)) * 8;
        af[t]  = *(const short8*)(Al[cur] + (wm + t * 16 + ln) * 64 + cx);
        bfr[t] = *(const short8*)(Bl[cur] + (wn + t * 16 + ln) * 64 + cx);
      }
#pragma unroll
      for (int mt = 0; mt < 4; mt++)
#pragma unroll
        for (int nt = 0; nt < 4; nt++)
          acc[mt][nt] = __builtin_amdgcn_mfma_f32_16x16x32_bf16(
              af[mt], bfr[nt], acc[mt][nt], 0, 0, 0);
    }
    __syncthreads();   // reads of cur done; DMA for cur^1 drained
    cur ^= 1;
  }

  if (bn < 512) {
#pragma unroll
    for (int mt = 0; mt < 4; mt++)
#pragma unroll
      for (int nt = 0; nt < 4; nt++)
#pragma unroll
        for (int r = 0; r < 4; r++) {
          int m = bm + wm + mt * 16 + quad * 4 + r;
          int n = bn + wn + nt * 16 + ln;
          qb[(size_t)m * 512 + n] = f2bs(acc[mt][nt][r] * 0.125f);
        }
  } else if (bn < 1024) {
#pragma unroll
    for (int mt = 0; mt < 4; mt++)
#pragma unroll
      for (int nt = 0; nt < 4; nt++)
#pragma unroll
        for (int r = 0; r < 4; r++) {
          int m = bm + wm + mt * 16 + quad * 4 + r;
          int n = bn - 512 + wn + nt * 16 + ln;
          kb[(size_t)m * 512 + n] = f2bs(acc[mt][nt][r]);
        }
  } else {
#pragma unroll
    for (int mt = 0; mt < 4; mt++)
#pragma unroll
      for (int nt = 0; nt < 4; nt++) {
        int vcol = bn - 1024 + wn + nt * 16 + ln;
        int m0 = bm + wm + mt * 16 + quad * 4;
        uint2 val;
        val.x = (uint)f2bs(acc[mt][nt][0]) | ((uint)f2bs(acc[mt][nt][1]) << 16);
        val.y = (uint)f2bs(acc[mt][nt][2]) | ((uint)f2bs(acc[mt][nt][3]) << 16);
        *(uint2*)(vtb + (size_t)vcol * 3072 + m0) = val;
      }
  }
}

// ---------------------------------------------------------------------------
// Output MFMA GEMM: att(bf16) @ Wot + bo -> f32 out.  Same v9 core.
// XCD-chunked swizzle (grid 288 = 8 x 36).
// ---------------------------------------------------------------------------
__global__ __launch_bounds__(256) void gemm_out(
    const ushort* __restrict__ att, const ushort* __restrict__ Wot,
    const float* __restrict__ bo, float* __restrict__ out) {
  __shared__ ushort Al[2][128 * 64];
  __shared__ ushort Bl[2][128 * 64];
  const int tid = threadIdx.x;
  const int w = tid >> 6, lane = tid & 63, quad = lane >> 4, ln = lane & 15;
  const int lr = lane >> 3, lcx = (lane & 7) ^ lr;
  const int Lb = blockIdx.x + 12 * blockIdx.y;          // 0..287
  const int wg = (Lb & 7) * 36 + (Lb >> 3);             // bijective (288%8==0)
  const int bm = (wg % 24) * 128, bn = (wg / 24) * 128;
  const int wm = (w & 1) * 64, wn = (w >> 1) * 64;
  f32x4 acc[4][4];
#pragma unroll
  for (int i = 0; i < 4; i++)
#pragma unroll
    for (int j = 0; j < 4; j++) acc[i][j] = (f32x4){0.f, 0.f, 0.f, 0.f};

  STAGE64(att, bm, 0, Al[0]);
  STAGE64(Wot, bn, 0, Bl[0]);
  __syncthreads();

  int cur = 0;
  for (int k0 = 0; k0 < 1536; k0 += 64) {
    if (k0 + 64 < 1536) {
      STAGE64(att, bm, k0 + 64, Al[cur ^ 1]);
      STAGE64(Wot, bn, k0 + 64, Bl[cur ^ 1]);
    }
#pragma unroll
    for (int ks = 0; ks < 2; ks++) {
      short8 af[4], bfr[4];
#pragma unroll
      for (int t = 0; t < 4; t++) {
        int cx = ((quad + 4 * ks) ^ (ln & 7)) * 8;
        af[t]  = *(const short8*)(Al[cur] + (wm + t * 16 + ln) * 64 + cx);
        bfr[t] = *(const short8*)(Bl[cur] + (wn + t * 16 + ln) * 64 + cx);
      }
#pragma unroll
      for (int mt = 0; mt < 4; mt++)
#pragma unroll
        for (int nt = 0; nt < 4; nt++)
          acc[mt][nt] = __builtin_amdgcn_mfma_f32_16x16x32_bf16(
              af[mt], bfr[nt], acc[mt][nt], 0, 0, 0);
    }
    __syncthreads();
    cur ^= 1;
  }
#pragma unroll
  for (int mt = 0; mt < 4; mt++)
#pragma unroll
    for (int nt = 0; nt < 4; nt++)
#pragma unroll
      for (int r = 0; r < 4; r++) {
        int m = bm + wm + mt * 16 + quad * 4 + r;
        int n = bn + wn + nt * 16 + ln;
        out[(size_t)m * 1536 + n] = acc[mt][nt][r] + bo[n];
      }
}

// ---------------------------------------------------------------------------
// MFMA flash attention, split-K(x2), t-tile 64, 4 waves, DMA staging.
// XCD-AWARE SWIZZLE: linear block id L -> xcd = L&7 owns head h = xcd only.
//
// v11: PV SPLIT BY V-COLUMNS. Wave w computes v-cols [48w,48w+48) for ALL 64
// t-rows (was: all 192 cols for own 16 rows). Each V row is now read ONCE per
// block (PV B-traffic 24KB->6KB/wave); P fragments read cross-wave from LDS
// (visible after bar#1 -> the same-wave lgkmcnt Pp round-trip is gone).
// Per-row alpha/l published via alphal[64]/needl[4] (block-uniform defer-max).
// Sum order per output element unchanged -> bit-identical results.
// Schedule:
//   S MFMAs on Kl (dval prefetched) -> softmax own rows -> Pp/alphal/needl
//   bar#1 (drains V(ch); Kl free; Pp visible) -> issue K(ch+1)
//   block-uniform Oacc rescale -> afr[4] cross-wave -> PV+Lacc (covers K DMA)
//   bar#2 (Vl free; K(ch+1) drained) -> issue V(ch+1) -> gather dval(ch+1)
// LDS [50448B]: K[64]x128B @0, V[192]x128B @8192, D[64][40]bf16 @32768,
//   LUT[3072]u8 @37888, per-wave Pp bf16[16][72] @40960, alphal f32[64]
//   @50176, needl i32[4] @50432.  3 blocks/CU.
// XOR swizzle (K/V): 16B chunk c of row r stored at physical chunk c^(r&7).
// ---------------------------------------------------------------------------
__global__ __launch_bounds__(256, 3) void attn_mfma(
    const ushort* __restrict__ qb, const ushort* __restrict__ kb,
    const ushort* __restrict__ vtb, const ushort* __restrict__ rkdb,
    const unsigned char* __restrict__ lutb,
    const float* __restrict__ rwb, const float* __restrict__ rrb,
    ushort* __restrict__ op0, ushort* __restrict__ op1,
    float2* __restrict__ mlb) {
  __shared__ __align__(16) char smem[50448];
  ushort* Kl = (ushort*)smem;                        // [64] rows x 128B
  ushort* Vl = (ushort*)(smem + 8192);               // [192] rows x 128B
  ushort* Dl = (ushort*)(smem + 32768);              // [64][40] bf16
  unsigned char* Ll = (unsigned char*)(smem + 37888);// [3072] u8
  float* alphal = (float*)(smem + 50176);            // [64] per-row alpha / l
  int* needl = (int*)(smem + 50432);                 // [4] per-wave rescale flag

  const int L  = blockIdx.x + 24 * blockIdx.y + 192 * blockIdx.z;
  const int h  = L & 7;                     // XCD id under round-robin
  const int g  = L >> 3;
  const int bsk = g / 24;
  const int b  = bsk >> 1;
  const int sk = bsk & 1;
  const int t0 = (g - bsk * 24) * 64;
  const int bT = b * Tn;
  const int tid = threadIdx.x;
  const int w = tid >> 6, lane = tid & 63, quad = lane >> 4, ln = lane & 15;

  ushort* Pp = (ushort*)(smem + 40960 + w * 2304);   // [16][72] bf16 per wave

  const int lr  = lane >> 3;          // staging: row-in-chunk 0..7
  const int lcx = (lane & 7) ^ lr;    // staging: logical 16B chunk (swizzle)

  // ---- prologue staging: K(0), V(0), LUT ----
  {
    const int s0 = sk * 768;
#pragma unroll
    for (int i = 0; i < 2; i++) {
      int kc = w * 2 + i, sr = kc * 8 + lr;
      gld_lds16(kb + (size_t)(bT + s0 + sr) * 512 + h * 64 + lcx * 8,
                (ushort*)(smem + kc * 1024) + lane * 8);
    }
#pragma unroll
    for (int i = 0; i < 6; i++) {
      int kc = w * 6 + i, vr = kc * 8 + lr;
      gld_lds16(vtb + (size_t)(h * 192 + vr) * 3072 + bT + s0 + lcx * 8,
                (ushort*)(smem + 8192 + kc * 1024) + lane * 8);
    }
    if (w < 3)
      gld_lds16((const ushort*)(lutb + w * 1024) + lane * 8,
                (ushort*)(smem + 37888 + w * 1024) + lane * 8);
  }

  // Q fragments (A-layout m=ln, k=quad*8+ks*32+e): content bias + rel bias
  short8 qw8[2], qr8[2];
  {
    const ushort* qrow = qb + (size_t)(bT + t0 + 16 * w + ln) * 512 + h * 64;
#pragma unroll
    for (int ks = 0; ks < 2; ks++) {
      int k0 = quad * 8 + ks * 32;
#pragma unroll
      for (int e = 0; e < 8; e++) {
        float qv = bs2f(qrow[k0 + e]);
        qw8[ks][e] = (short)f2bs(qv + rwb[h * 64 + k0 + e]);
        qr8[ks][e] = (short)f2bs(qv + rrb[h * 64 + k0 + e]);
      }
    }
  }

  // ---- D table via MFMA: D[t][u] = (q+rrb) . rkd[h][u], u<33 (pad rows=0) --
  {
    f32x4 Dacc[3];
#pragma unroll
    for (int ut = 0; ut < 3; ut++) {
      Dacc[ut] = (f32x4){0.f, 0.f, 0.f, 0.f};
#pragma unroll
      for (int ks = 0; ks < 2; ks++) {
        int urow = 16 * ut + ln; urow = urow > 39 ? 39 : urow;  // rows>=33 are 0
        short8 bfr = *(const short8*)(rkdb + h * 2560 + urow * 64 + quad * 8 + ks * 32);
        Dacc[ut] = __builtin_amdgcn_mfma_f32_16x16x32_bf16(qr8[ks], bfr, Dacc[ut], 0, 0, 0);
      }
    }
    const int trow = 16 * w + 4 * quad;   // wave-local t rows (C: m=4*quad+r)
#pragma unroll
    for (int ut = 0; ut < 2; ut++)
#pragma unroll
      for (int r = 0; r < 4; r++)
        Dl[(trow + r) * 40 + 16 * ut + ln] = f2bs(Dacc[ut][r]);
    if (ln == 0) {
#pragma unroll
      for (int r = 0; r < 4; r++)
        Dl[(trow + r) * 40 + 32] = f2bs(Dacc[2][r]);
    }
  }

  // Oacc[mt][vt2]: rows t = t0+16mt+4quad+r, cols v = 48w+16vt2+ln
  f32x4 Oacc[4][3];
  f32x4 Lacc = (f32x4){0.f, 0.f, 0.f, 0.f};   // own-row l via ones-MFMA
  float m_i[4];
#pragma unroll
  for (int mt = 0; mt < 4; mt++)
#pragma unroll
    for (int vt2 = 0; vt2 < 3; vt2++) Oacc[mt][vt2] = (f32x4){0.f, 0.f, 0.f, 0.f};
#pragma unroll
  for (int r = 0; r < 4; r++) m_i[r] = -1e30f;

  short8 ones8;
#pragma unroll
  for (int e = 0; e < 8; e++) ones8[e] = (short)0x3F80;   // bf16 1.0

  __syncthreads();   // K(0)/V(0)/LUT staged; Dl writes visible

  const int ibase = sk * 768 - t0 - 16 * w - 4 * quad + ln + 1535;
  const int tl0 = 16 * w + 4 * quad;

  // ---- prologue gather: dval for ch = 0 (Dl/Ll static from here on) ----
  float dval[4][4];
#pragma unroll
  for (int ct = 0; ct < 4; ct++)
#pragma unroll
    for (int r = 0; r < 4; r++) {
      int idx = ibase + 16 * ct - r;
      dval[ct][r] = bs2f(Dl[(tl0 + r) * 40 + Ll[idx]]);
    }

  for (int ch = 0; ch < 12; ch++) {
    // ---- S phase: content logits (reads Kl) ----
    f32x4 Sacc[4];
    __builtin_amdgcn_s_setprio(1);
#pragma unroll
    for (int ct = 0; ct < 4; ct++) {
      Sacc[ct] = (f32x4){0.f, 0.f, 0.f, 0.f};
#pragma unroll
      for (int ks = 0; ks < 2; ks++) {
        short8 bfr = *(const short8*)(
            Kl + (16 * ct + ln) * 64 + ((quad + 4 * ks) ^ (ln & 7)) * 8);
        Sacc[ct] = __builtin_amdgcn_mfma_f32_16x16x32_bf16(qw8[ks], bfr, Sacc[ct], 0, 0, 0);
      }
    }
    __builtin_amdgcn_s_setprio(0);

    float pS[4][4];
#pragma unroll
    for (int ct = 0; ct < 4; ct++)
#pragma unroll
      for (int r = 0; r < 4; r++)
        pS[ct][r] = Sacc[ct][r] + dval[ct][r];

    // ---- softmax own rows: DPP max + defer-max (THR=8) ----
    float mx[4];
#pragma unroll
    for (int r = 0; r < 4; r++) {
      float m2 = fmaxf(fmaxf(pS[0][r], pS[1][r]), fmaxf(pS[2][r], pS[3][r]));
      DPP_MAXSTEP(m2, 0xB1);    // quad_perm [1,0,3,2]  (xor 1)
      DPP_MAXSTEP(m2, 0x4E);    // quad_perm [2,3,0,1]  (xor 2)
      DPP_MAXSTEP(m2, 0x124);   // row_ror:4
      DPP_MAXSTEP(m2, 0x128);   // row_ror:8
      mx[r] = m2;
    }
    int need = (mx[0] > m_i[0] + 8.f) | (mx[1] > m_i[1] + 8.f) |
               (mx[2] > m_i[2] + 8.f) | (mx[3] > m_i[3] + 8.f);
    int anyw = __any(need);
    float alpha[4];
    if (anyw) {
#pragma unroll
      for (int r = 0; r < 4; r++) {
        float mnew = fmaxf(m_i[r], mx[r]);
        alpha[r] = __expf(m_i[r] - mnew);
        m_i[r] = mnew;
      }
    } else {
#pragma unroll
      for (int r = 0; r < 4; r++) alpha[r] = 1.f;
    }
#pragma unroll
    for (int ct = 0; ct < 4; ct++)
#pragma unroll
      for (int r = 0; r < 4; r++)
        pS[ct][r] = __expf(pS[ct][r] - m_i[r]);
#pragma unroll
    for (int r = 0; r < 4; r++) Lacc[r] *= alpha[r];
    // publish probs + per-row alpha + per-wave need flag
#pragma unroll
    for (int ct = 0; ct < 4; ct++)
#pragma unroll
      for (int r = 0; r < 4; r++)
        Pp[(4 * quad + r) * 72 + 16 * ct + ln] = f2bs(pS[ct][r]);
    if (ln == 0) {
#pragma unroll
      for (int r = 0; r < 4; r++) alphal[16 * w + 4 * quad + r] = alpha[r];
    }
    if (lane == 0) needl[w] = anyw;

    __syncthreads();   // #1: Kl free (S done); V(ch) drained; Pp/alphal visible

    // ---- issue K(ch+1) DMA (covered by rescale + PV) ----
    if (ch < 11) {
      const int s0n = sk * 768 + ch * 64 + 64;
#pragma unroll
      for (int i = 0; i < 2; i++) {
        int kc = w * 2 + i, sr = kc * 8 + lr;
        gld_lds16(kb + (size_t)(bT + s0n + sr) * 512 + h * 64 + lcx * 8,
                  (ushort*)(smem + kc * 1024) + lane * 8);
      }
    }

    // ---- block-uniform Oacc rescale (skipped when no wave re-maxed) ----
    if (needl[0] | needl[1] | needl[2] | needl[3]) {
#pragma unroll
      for (int mt = 0; mt < 4; mt++) {
        float al[4];
#pragma unroll
        for (int r = 0; r < 4; r++) al[r] = alphal[16 * mt + 4 * quad + r];
#pragma unroll
        for (int vt2 = 0; vt2 < 3; vt2++)
#pragma unroll
          for (int r = 0; r < 4; r++) Oacc[mt][vt2][r] *= al[r];
      }
    }

    // ---- A fragments: all 4 waves' P rows (cross-wave via LDS) ----
    short8 afr[4][2];
#pragma unroll
    for (int mt = 0; mt < 4; mt++) {
      const ushort* Pmt = (const ushort*)(smem + 40960 + mt * 2304);
      afr[mt][0] = *(const short8*)(Pmt + ln * 72 + quad * 8);
      afr[mt][1] = *(const short8*)(Pmt + ln * 72 + quad * 8 + 32);
    }
    // own-row fragment for Lacc (separate load keeps afr[] indices static)
    short8 ownA0 = *(const short8*)(Pp + ln * 72 + quad * 8);
    short8 ownA1 = *(const short8*)(Pp + ln * 72 + quad * 8 + 32);

    // ---- PV phase: v-col stripe [48w, 48w+48) x all 64 t-rows ----
    __builtin_amdgcn_s_setprio(1);
    Lacc = __builtin_amdgcn_mfma_f32_16x16x32_bf16(ownA0, ones8, Lacc, 0, 0, 0);
    Lacc = __builtin_amdgcn_mfma_f32_16x16x32_bf16(ownA1, ones8, Lacc, 0, 0, 0);
#pragma unroll
    for (int vt2 = 0; vt2 < 3; vt2++) {
      int vrow = (48 * w + 16 * vt2 + ln) * 64;
      short8 b0 = *(const short8*)(Vl + vrow + ((quad + 0) ^ (ln & 7)) * 8);
      short8 b1 = *(const short8*)(Vl + vrow + ((quad + 4) ^ (ln & 7)) * 8);
#pragma unroll
      for (int mt = 0; mt < 4; mt++) {
        Oacc[mt][vt2] = __builtin_amdgcn_mfma_f32_16x16x32_bf16(
            afr[mt][0], b0, Oacc[mt][vt2], 0, 0, 0);
        Oacc[mt][vt2] = __builtin_amdgcn_mfma_f32_16x16x32_bf16(
            afr[mt][1], b1, Oacc[mt][vt2], 0, 0, 0);
      }
    }
    __builtin_amdgcn_s_setprio(0);

    __syncthreads();   // #2: Vl free (PV done); K(ch+1) drained

    // ---- issue V(ch+1) DMA + prefetch gather of dval(ch+1) ----
    if (ch < 11) {
      const int s0n = sk * 768 + ch * 64 + 64;
#pragma unroll
      for (int i = 0; i < 6; i++) {
        int kc = w * 6 + i, vr = kc * 8 + lr;
        gld_lds16(vtb + (size_t)(h * 192 + vr) * 3072 + bT + s0n + lcx * 8,
                  (ushort*)(smem + 8192 + kc * 1024) + lane * 8);
      }
#pragma unroll
      for (int ct = 0; ct < 4; ct++)
#pragma unroll
        for (int r = 0; r < 4; r++) {
          int idx = ibase + 64 * (ch + 1) + 16 * ct - r;
          dval[ct][r] = bs2f(Dl[(tl0 + r) * 40 + Ll[idx]]);
        }
    }
  }

  // ---- epilogue: publish l (reuse alphal), then normalized bf16 stripe ----
  if (ln == 0) {
#pragma unroll
    for (int r = 0; r < 4; r++) alphal[16 * w + 4 * quad + r] = Lacc[r];
  }
  __syncthreads();
  ushort* op = sk ? op1 : op0;
#pragma unroll
  for (int mt = 0; mt < 4; mt++) {
    float inv[4];
#pragma unroll
    for (int r = 0; r < 4; r++) inv[r] = 1.f / alphal[16 * mt + 4 * quad + r];
#pragma unroll
    for (int vt2 = 0; vt2 < 3; vt2++)
#pragma unroll
      for (int r = 0; r < 4; r++) {
        int t = t0 + 16 * mt + 4 * quad + r;
        op[(size_t)(bT + t) * 1536 + h * 192 + 48 * w + 16 * vt2 + ln] =
            f2bs(Oacc[mt][vt2][r] * inv[r]);
      }
  }
  if (ln == 0) {
#pragma unroll
    for (int r = 0; r < 4; r++) {
      int t = t0 + 16 * w + 4 * quad + r;
      float2 v; v.x = m_i[r]; v.y = Lacc[r];
      mlb[((sk * 2 + b) * 8 + h) * 1536 + t] = v;
    }
  }
}

// ---------------------------------------------------------------------------
// Combine the two split-K partials: O = sum_i e^{m_i-M} l_i O_i / sum e^{m-M} l
// ---------------------------------------------------------------------------
__global__ __launch_bounds__(256) void attn_combine(
    const ushort* __restrict__ op0, const ushort* __restrict__ op1,
    const float2* __restrict__ mlb, ushort* __restrict__ att) {
  int g = blockIdx.x * 256 + threadIdx.x;   // group of 4 bf16
  int row = g / 384;                        // 0..3071
  int c4 = (g - row * 384) * 4;             // 0..1532
  int b = row >= 1536;
  int t = row - b * 1536;
  int h = c4 / 192;
  float2 ml0 = mlb[((0 + b) * 8 + h) * 1536 + t];
  float2 ml1 = mlb[((2 + b) * 8 + h) * 1536 + t];
  float M = fmaxf(ml0.x, ml1.x);
  float w0 = __expf(ml0.x - M) * ml0.y;
  float w1 = __expf(ml1.x - M) * ml1.y;
  float inv = 1.f / (w0 + w1);
  w0 *= inv; w1 *= inv;
  size_t off = (size_t)row * 1536 + c4;
  uint2 a = *(const uint2*)(op0 + off);
  uint2 c = *(const uint2*)(op1 + off);
  uint2 o;
  float r0 = w0 * bs2f((ushort)(a.x & 0xffff)) + w1 * bs2f((ushort)(c.x & 0xffff));
  float r1 = w0 * bs2f((ushort)(a.x >> 16))    + w1 * bs2f((ushort)(c.x >> 16));
  float r2 = w0 * bs2f((ushort)(a.y & 0xffff)) + w1 * bs2f((ushort)(c.y & 0xffff));
  float r3 = w0 * bs2f((ushort)(a.y >> 16))    + w1 * bs2f((ushort)(c.y >> 16));
  o.x = (uint)f2bs(r0) | ((uint)f2bs(r1) << 16);
  o.y = (uint)f2bs(r2) | ((uint)f2bs(r3) << 16);
  *(uint2*)(att + off) = o;
}

// ---------------------------------------------------------------------------
extern "C" void kernel_launch(void* const* d_in, const int* in_sizes, int n_in,
                              void* d_out, int out_size, void* d_ws, size_t ws_size,
                              hipStream_t stream) {
  const float* x   = (const float*)d_in[0];
  const float* Wq  = (const float*)d_in[1];
  const float* Wk  = (const float*)d_in[2];
  const float* Wv  = (const float*)d_in[3];
  const float* Wr  = (const float*)d_in[4];
  const float* rwb = (const float*)d_in[5];
  const float* rrb = (const float*)d_in[6];
  const float* Wo  = (const float*)d_in[7];
  const float* bo  = (const float*)d_in[8];
  float* out = (float*)d_out;

  char* ws = (char*)d_ws;
  // Region A [0, 9437184): xb (prep->qkv) -> op1 (attn) -> att (combine, same
  // addresses elementwise) -> gemm_out input.
  ushort* xb  = (ushort*)ws;
  ushort* op1 = (ushort*)ws;
  ushort* att = (ushort*)ws;
  ushort* Wot = (ushort*)(ws + 9437184);    // [1536][1536] bf16, until gemm_out
  ushort* Wt  = (ushort*)(ws + 14155776);   // [2560][1536] bf16, until gemm_qkv
  ushort* op0 = (ushort*)(ws + 14155776);   // overlays dead Wt (attn phase)
  ushort* qb  = (ushort*)(ws + 23592960);   // [3072][512] bf16 (scaled)
  ushort* kb  = (ushort*)(ws + 26738688);   // [3072][512] bf16
  ushort* vtb = (ushort*)(ws + 29884416);   // [1536][3072] bf16 (V^T)
  unsigned char* lutb = (unsigned char*)(ws + 41287680);  // [3072] u8
  ushort* rkdb = (ushort*)(ws + 41290752);  // [8][40][64] bf16 (40KB)
  float2* mlb = (float2*)(ws + 42467328);   // [2][2][8][1536] (m,l)

  prep<<<dim3(48, 48, 6), dim3(256), 0, stream>>>(
      x, Wq, Wk, Wv, Wo, Wr, xb, Wt, Wot, rkdb, lutb);
  gemm_qkv<<<dim3(20, 24), dim3(256), 0, stream>>>(xb, Wt, qb, kb, vtb);
  attn_mfma<<<dim3(24, 8, 4), dim3(256), 0, stream>>>(
      qb, kb, vtb, rkdb, lutb, rwb, rrb, op0, op1, mlb);
  attn_combine<<<dim3(4608), dim3(256), 0, stream>>>(op0, op1, mlb, att);
  gemm_out<<<dim3(12, 24), dim3(256), 0, stream>>>(att, Wot, bo, out);
}

// Round 13
// 211.160 us; speedup vs baseline: 1.0165x; 1.0165x over previous
//
#include <hip/hip_runtime.h>
#include <hip/hip_bf16.h>

typedef __hip_bfloat16 bf16;
typedef unsigned short ushort;
typedef unsigned int uint;
typedef __attribute__((ext_vector_type(8))) short short8;
typedef __attribute__((ext_vector_type(4))) float f32x4;

#define Bsz 2
#define Tn  1536
#define Cn  1536
#define Hn  8
#define Kn  64
#define Vn  192
// H*K = 512, H*V = 1536, 2T-1 = 3071

__device__ __forceinline__ ushort f2bs(float f) {
  union { bf16 h; ushort u; } cv;
  cv.h = __float2bfloat16(f);
  return cv.u;
}
__device__ __forceinline__ float bs2f(ushort u) {
  union { float f; uint v; } cv; cv.v = ((uint)u) << 16; return cv.f;
}

// async global->LDS, 16B per lane; LDS dest = wave-uniform base + lane*16
__device__ __forceinline__ void gld_lds16(const ushort* g, ushort* l) {
  __builtin_amdgcn_global_load_lds(
      (const __attribute__((address_space(1))) uint*)g,
      (__attribute__((address_space(3))) uint*)l, 16, 0, 0);
}

// 16-lane max-reduce step via DPP (VALU-rate, no LDS): x = max(x, dpp(x))
#define DPP_MAXSTEP(x, ctrl)                                                  \
  do {                                                                        \
    union { float f; int i; } a_, b_;                                         \
    a_.f = (x);                                                               \
    b_.i = __builtin_amdgcn_update_dpp(a_.i, a_.i, (ctrl), 0xf, 0xf, true);   \
    (x) = fmaxf((x), b_.f);                                                   \
  } while (0)

// ---------------------------------------------------------------------------
// Merged prep kernel, grid (48,48,6):
//  z=0..3: transpose+cvt  W{q,k,v,o} f32 [1536][Cc] -> bf16 [Cc][1536]
//  z=4   : x f32 -> xb bf16 (vectorized x4, grid-stride)
//  z=5   : rkd[8][40][64] bf16 (33 DISTINCT rel-basis rows per head; rows
//          33..39 ZERO pad) and lutb[3072] u8: d+1535 -> row index u.
// ---------------------------------------------------------------------------
__global__ __launch_bounds__(256) void prep(
    const float* __restrict__ x,  const float* __restrict__ Wq,
    const float* __restrict__ Wk, const float* __restrict__ Wv,
    const float* __restrict__ Wo, const float* __restrict__ Wr,
    ushort* __restrict__ xb, ushort* __restrict__ Wt,
    ushort* __restrict__ Wot, ushort* __restrict__ rkdb,
    unsigned char* __restrict__ lutb) {
  const int z = blockIdx.z;
  if (z < 4) {
    if (z < 2 && blockIdx.x >= 16) return;
    const float* in = (z == 0) ? Wq : (z == 1) ? Wk : (z == 2) ? Wv : Wo;
    ushort* out = (z == 0) ? Wt : (z == 1) ? Wt + 512 * 1536
                : (z == 2) ? Wt + 1024 * 1536 : Wot;
    const int Cc = (z < 2) ? 512 : 1536;
    __shared__ float tile[32][33];
    const int bx = blockIdx.x * 32;
    const int by = blockIdx.y * 32;
    const int tx = threadIdx.x & 31, ty = threadIdx.x >> 5;
#pragma unroll
    for (int i = 0; i < 32; i += 8)
      tile[ty + i][tx] = in[(size_t)(by + ty + i) * Cc + bx + tx];
    __syncthreads();
#pragma unroll
    for (int i = 0; i < 32; i += 8)
      out[(size_t)(bx + ty + i) * 1536 + by + tx] = f2bs(tile[tx][ty + i]);
  } else if (z == 4) {
    const int n4 = 3072 * 1536 / 4;
    for (int i = (blockIdx.y * 48 + blockIdx.x) * 256 + threadIdx.x; i < n4;
         i += 2304 * 256) {
      float4 v = ((const float4*)x)[i];
      uint2 o;
      o.x = (uint)f2bs(v.x) | ((uint)f2bs(v.y) << 16);
      o.y = (uint)f2bs(v.z) | ((uint)f2bs(v.w) << 16);
      ((uint2*)xb)[i] = o;
    }
  } else {
    const int base = (blockIdx.y * 48 + blockIdx.x) * 256 + threadIdx.x;
    if (base < 8 * 40 * 64) {
      // rkd entry: h, u-row (pad 33..39 = 0), k
      const int h = base / 2560, rem = base % 2560, u = rem >> 6, k = rem & 63;
      float acc = 0.f;
      if (u < 33) {
        const float sg = (u == 32) ? 0.f : (u < 16 ? 1.f : -1.f);
        const int c = (u == 32) ? 16 : (u < 16 ? u + 1 : u - 15);
        // active features are the c LARGEST widths: i = 16-c .. 15 (ascending,
        // same summation order as the original rkb builder)
#pragma unroll
        for (int i = 0; i < 16; i++)
          if (i >= 16 - c)
            acc += Wr[i * 512 + h * 64 + k] + sg * Wr[(16 + i) * 512 + h * 64 + k];
      }
      rkdb[h * 2560 + u * 64 + k] = f2bs(acc);
    } else if (base < 8 * 40 * 64 + 3072) {
      const int idx = base - 8 * 40 * 64;       // 0..3071 (3071 = pad)
      const int d = idx - 1535;
      const float ad = fabsf((float)d);
      int c = 0;
#pragma unroll
      for (int i = 0; i < 16; i++) {
        double cw = exp(log((double)(Tn + 1)) * (double)(i + 1) / 16.0) - 1.0;
        if ((float)cw > ad) c++;
      }
      lutb[idx] = (unsigned char)((d == 0) ? 32 : (d > 0 ? c - 1 : 15 + c));
    }
  }
}

// ---------------------------------------------------------------------------
// v9 GEMM core: 128x128 tile, BK=64, DOUBLE-BUFFERED LDS (T3-minimum 2-phase:
// issue next-tile DMA -> compute current -> one barrier/iter; drain covered).
// 128B rows would be a 16-way ds_read conflict -> attn-style XOR swizzle (T2):
// global 16B chunk c of row r staged at physical chunk c^(r&7); ds_read col
// chunk (quad+4ks)^(ln&7). LDS 64KB (2 blocks/CU cap; grids are ~1-2/CU).
// STAGE64: one [128r x 64k] bf16 tile = 16 chunks of 1KB; 4 per wave.
// ---------------------------------------------------------------------------
#define STAGE64(src, base_row, kk, dst)                                       \
  _Pragma("unroll")                                                           \
  for (int i_ = 0; i_ < 4; i_++) {                                            \
    int kc_ = w * 4 + i_, sr_ = kc_ * 8 + lr;                                 \
    gld_lds16(src + (size_t)(base_row + sr_) * 1536 + (kk) + lcx * 8,         \
              dst + kc_ * 512 + lane * 8);                                    \
  }

// ---------------------------------------------------------------------------
// Fused QKV MFMA GEMM: xb @ Wt^T-layout -> qb/kb/vtb.
// XCD-chunked block swizzle (grid 480 = 8 x 60).
// ---------------------------------------------------------------------------
__global__ __launch_bounds__(256) void gemm_qkv(
    const ushort* __restrict__ xb, const ushort* __restrict__ Wt,
    ushort* __restrict__ qb, ushort* __restrict__ kb, ushort* __restrict__ vtb) {
  __shared__ ushort Al[2][128 * 64];
  __shared__ ushort Bl[2][128 * 64];
  const int tid = threadIdx.x;
  const int w = tid >> 6, lane = tid & 63, quad = lane >> 4, ln = lane & 15;
  const int lr = lane >> 3, lcx = (lane & 7) ^ lr;
  const int Lb = blockIdx.x + 20 * blockIdx.y;          // 0..479
  const int wg = (Lb & 7) * 60 + (Lb >> 3);             // bijective (480%8==0)
  const int bm = (wg % 24) * 128, bn = (wg / 24) * 128;
  const int wm = (w & 1) * 64, wn = (w >> 1) * 64;
  f32x4 acc[4][4];
#pragma unroll
  for (int i = 0; i < 4; i++)
#pragma unroll
    for (int j = 0; j < 4; j++) acc[i][j] = (f32x4){0.f, 0.f, 0.f, 0.f};

  STAGE64(xb, bm, 0, Al[0]);
  STAGE64(Wt, bn, 0, Bl[0]);
  __syncthreads();

  int cur = 0;
  for (int k0 = 0; k0 < 1536; k0 += 64) {
    if (k0 + 64 < 1536) {
      STAGE64(xb, bm, k0 + 64, Al[cur ^ 1]);
      STAGE64(Wt, bn, k0 + 64, Bl[cur ^ 1]);
    }
#pragma unroll
    for (int ks = 0; ks < 2; ks++) {
      short8 af[4], bfr[4];
#pragma unroll
      for (int t = 0; t < 4; t++) {
        int cx = ((quad + 4 * ks) ^ (ln & 7)) * 8;
        af[t]  = *(const short8*)(Al[cur] + (wm + t * 16 + ln) * 64 + cx);
        bfr[t] = *(const short8*)(Bl[cur] + (wn + t * 16 + ln) * 64 + cx);
      }
#pragma unroll
      for (int mt = 0; mt < 4; mt++)
#pragma unroll
        for (int nt = 0; nt < 4; nt++)
          acc[mt][nt] = __builtin_amdgcn_mfma_f32_16x16x32_bf16(
              af[mt], bfr[nt], acc[mt][nt], 0, 0, 0);
    }
    __syncthreads();   // reads of cur done; DMA for cur^1 drained
    cur ^= 1;
  }

  if (bn < 512) {
#pragma unroll
    for (int mt = 0; mt < 4; mt++)
#pragma unroll
      for (int nt = 0; nt < 4; nt++)
#pragma unroll
        for (int r = 0; r < 4; r++) {
          int m = bm + wm + mt * 16 + quad * 4 + r;
          int n = bn + wn + nt * 16 + ln;
          qb[(size_t)m * 512 + n] = f2bs(acc[mt][nt][r] * 0.125f);
        }
  } else if (bn < 1024) {
#pragma unroll
    for (int mt = 0; mt < 4; mt++)
#pragma unroll
      for (int nt = 0; nt < 4; nt++)
#pragma unroll
        for (int r = 0; r < 4; r++) {
          int m = bm + wm + mt * 16 + quad * 4 + r;
          int n = bn - 512 + wn + nt * 16 + ln;
          kb[(size_t)m * 512 + n] = f2bs(acc[mt][nt][r]);
        }
  } else {
#pragma unroll
    for (int mt = 0; mt < 4; mt++)
#pragma unroll
      for (int nt = 0; nt < 4; nt++) {
        int vcol = bn - 1024 + wn + nt * 16 + ln;
        int m0 = bm + wm + mt * 16 + quad * 4;
        uint2 val;
        val.x = (uint)f2bs(acc[mt][nt][0]) | ((uint)f2bs(acc[mt][nt][1]) << 16);
        val.y = (uint)f2bs(acc[mt][nt][2]) | ((uint)f2bs(acc[mt][nt][3]) << 16);
        *(uint2*)(vtb + (size_t)vcol * 3072 + m0) = val;
      }
  }
}

// ---------------------------------------------------------------------------
// Output MFMA GEMM: att(bf16) @ Wot + bo -> f32 out.  Same v9 core.
// XCD-chunked swizzle (grid 288 = 8 x 36).
// ---------------------------------------------------------------------------
__global__ __launch_bounds__(256) void gemm_out(
    const ushort* __restrict__ att, const ushort* __restrict__ Wot,
    const float* __restrict__ bo, float* __restrict__ out) {
  __shared__ ushort Al[2][128 * 64];
  __shared__ ushort Bl[2][128 * 64];
  const int tid = threadIdx.x;
  const int w = tid >> 6, lane = tid & 63, quad = lane >> 4, ln = lane & 15;
  const int lr = lane >> 3, lcx = (lane & 7) ^ lr;
  const int Lb = blockIdx.x + 12 * blockIdx.y;          // 0..287
  const int wg = (Lb & 7) * 36 + (Lb >> 3);             // bijective (288%8==0)
  const int bm = (wg % 24) * 128, bn = (wg / 24) * 128;
  const int wm = (w & 1) * 64, wn = (w >> 1) * 64;
  f32x4 acc[4][4];
#pragma unroll
  for (int i = 0; i < 4; i++)
#pragma unroll
    for (int j = 0; j < 4; j++) acc[i][j] = (f32x4){0.f, 0.f, 0.f, 0.f};

  STAGE64(att, bm, 0, Al[0]);
  STAGE64(Wot, bn, 0, Bl[0]);
  __syncthreads();

  int cur = 0;
  for (int k0 = 0; k0 < 1536; k0 += 64) {
    if (k0 + 64 < 1536) {
      STAGE64(att, bm, k0 + 64, Al[cur ^ 1]);
      STAGE64(Wot, bn, k0 + 64, Bl[cur ^ 1]);
    }
#pragma unroll
    for (int ks = 0; ks < 2; ks++) {
      short8 af[4], bfr[4];
#pragma unroll
      for (int t = 0; t < 4; t++) {
        int cx = ((quad + 4 * ks) ^ (ln & 7)) * 8;
        af[t]  = *(const short8*)(Al[cur] + (wm + t * 16 + ln) * 64 + cx);
        bfr[t] = *(const short8*)(Bl[cur] + (wn + t * 16 + ln) * 64 + cx);
      }
#pragma unroll
      for (int mt = 0; mt < 4; mt++)
#pragma unroll
        for (int nt = 0; nt < 4; nt++)
          acc[mt][nt] = __builtin_amdgcn_mfma_f32_16x16x32_bf16(
              af[mt], bfr[nt], acc[mt][nt], 0, 0, 0);
    }
    __syncthreads();
    cur ^= 1;
  }
#pragma unroll
  for (int mt = 0; mt < 4; mt++)
#pragma unroll
    for (int nt = 0; nt < 4; nt++)
#pragma unroll
      for (int r = 0; r < 4; r++) {
        int m = bm + wm + mt * 16 + quad * 4 + r;
        int n = bn + wn + nt * 16 + ln;
        out[(size_t)m * 1536 + n] = acc[mt][nt][r] + bo[n];
      }
}

// ---------------------------------------------------------------------------
// MFMA flash attention, split-K(x2), t-tile 64, 4 waves, DMA staging.
// XCD-AWARE SWIZZLE: linear block id L -> xcd = L&7 owns head h = xcd only.
// v12 = revert to the v9 attn (best measured: attn 46.0us, total 211.0us).
// v11's cross-wave PV split multiplied Pp-region LDS traffic x5 -> bank
// conflicts 295K -> 1.47M and regressed attn to 52.4us; reverted.
// Schedule:
//   gather (Dl/Ll) -> S MFMAs on Kl -> softmax(DPP, defer-max) -> Pp/afr
//   bar#1 (drains V(ch); Kl free) -> issue K(ch+1)
//   PV+Lacc MFMAs on Vl (covers K DMA)
//   bar#2 (drains K(ch+1); Vl free) -> issue V(ch+1)
// LDS [50176B]: K[64]x128B @0, V[192]x128B @8192, D[64][40]bf16 @32768,
//   LUT[3072]u8 @37888, per-wave Pp bf16[16][72] @40960.  3 blocks/CU.
// XOR swizzle (K/V): 16B chunk c of row r stored at physical chunk c^(r&7).
// ---------------------------------------------------------------------------
__global__ __launch_bounds__(256, 3) void attn_mfma(
    const ushort* __restrict__ qb, const ushort* __restrict__ kb,
    const ushort* __restrict__ vtb, const ushort* __restrict__ rkdb,
    const unsigned char* __restrict__ lutb,
    const float* __restrict__ rwb, const float* __restrict__ rrb,
    ushort* __restrict__ op0, ushort* __restrict__ op1,
    float2* __restrict__ mlb) {
  __shared__ __align__(16) char smem[50176];
  ushort* Kl = (ushort*)smem;                        // [64] rows x 128B
  ushort* Vl = (ushort*)(smem + 8192);               // [192] rows x 128B
  ushort* Dl = (ushort*)(smem + 32768);              // [64][40] bf16
  unsigned char* Ll = (unsigned char*)(smem + 37888);// [3072] u8

  const int L  = blockIdx.x + 24 * blockIdx.y + 192 * blockIdx.z;
  const int h  = L & 7;                     // XCD id under round-robin
  const int g  = L >> 3;
  const int bsk = g / 24;
  const int b  = bsk >> 1;
  const int sk = bsk & 1;
  const int t0 = (g - bsk * 24) * 64;
  const int bT = b * Tn;
  const int tid = threadIdx.x;
  const int w = tid >> 6, lane = tid & 63, quad = lane >> 4, ln = lane & 15;

  ushort* Pp = (ushort*)(smem + 40960 + w * 2304);   // [16][72] bf16 per wave

  const int lr  = lane >> 3;          // staging: row-in-chunk 0..7
  const int lcx = (lane & 7) ^ lr;    // staging: logical 16B chunk (swizzle)

  // ---- prologue staging: K(0), V(0), LUT ----
  {
    const int s0 = sk * 768;
#pragma unroll
    for (int i = 0; i < 2; i++) {
      int kc = w * 2 + i, sr = kc * 8 + lr;
      gld_lds16(kb + (size_t)(bT + s0 + sr) * 512 + h * 64 + lcx * 8,
                (ushort*)(smem + kc * 1024) + lane * 8);
    }
#pragma unroll
    for (int i = 0; i < 6; i++) {
      int kc = w * 6 + i, vr = kc * 8 + lr;
      gld_lds16(vtb + (size_t)(h * 192 + vr) * 3072 + bT + s0 + lcx * 8,
                (ushort*)(smem + 8192 + kc * 1024) + lane * 8);
    }
    if (w < 3)
      gld_lds16((const ushort*)(lutb + w * 1024) + lane * 8,
                (ushort*)(smem + 37888 + w * 1024) + lane * 8);
  }

  // Q fragments (A-layout m=ln, k=quad*8+ks*32+e): content bias + rel bias
  short8 qw8[2], qr8[2];
  {
    const ushort* qrow = qb + (size_t)(bT + t0 + 16 * w + ln) * 512 + h * 64;
#pragma unroll
    for (int ks = 0; ks < 2; ks++) {
      int k0 = quad * 8 + ks * 32;
#pragma unroll
      for (int e = 0; e < 8; e++) {
        float qv = bs2f(qrow[k0 + e]);
        qw8[ks][e] = (short)f2bs(qv + rwb[h * 64 + k0 + e]);
        qr8[ks][e] = (short)f2bs(qv + rrb[h * 64 + k0 + e]);
      }
    }
  }

  // ---- D table via MFMA: D[t][u] = (q+rrb) . rkd[h][u], u<33 (pad rows=0) --
  {
    f32x4 Dacc[3];
#pragma unroll
    for (int ut = 0; ut < 3; ut++) {
      Dacc[ut] = (f32x4){0.f, 0.f, 0.f, 0.f};
#pragma unroll
      for (int ks = 0; ks < 2; ks++) {
        int urow = 16 * ut + ln; urow = urow > 39 ? 39 : urow;  // rows>=33 are 0
        short8 bfr = *(const short8*)(rkdb + h * 2560 + urow * 64 + quad * 8 + ks * 32);
        Dacc[ut] = __builtin_amdgcn_mfma_f32_16x16x32_bf16(qr8[ks], bfr, Dacc[ut], 0, 0, 0);
      }
    }
    const int trow = 16 * w + 4 * quad;   // wave-local t rows (C: m=4*quad+r)
#pragma unroll
    for (int ut = 0; ut < 2; ut++)
#pragma unroll
      for (int r = 0; r < 4; r++)
        Dl[(trow + r) * 40 + 16 * ut + ln] = f2bs(Dacc[ut][r]);
    if (ln == 0) {
#pragma unroll
      for (int r = 0; r < 4; r++)
        Dl[(trow + r) * 40 + 32] = f2bs(Dacc[2][r]);
    }
  }

  f32x4 Oacc[12];
  f32x4 Lacc = (f32x4){0.f, 0.f, 0.f, 0.f};   // online l via ones-MFMA
  float m_i[4];
#pragma unroll
  for (int vt = 0; vt < 12; vt++) Oacc[vt] = (f32x4){0.f, 0.f, 0.f, 0.f};
#pragma unroll
  for (int r = 0; r < 4; r++) m_i[r] = -1e30f;

  short8 ones8;
#pragma unroll
  for (int e = 0; e < 8; e++) ones8[e] = (short)0x3F80;   // bf16 1.0

  __syncthreads();   // K(0)/V(0)/LUT staged; Dl writes visible

  const int ibase = sk * 768 - t0 - 16 * w - 4 * quad + ln + 1535;
  const int tl0 = 16 * w + 4 * quad;

  for (int ch = 0; ch < 12; ch++) {
    // ---- rel lookups (Dl/Ll static; independent of S MFMAs) ----
    float dval[4][4];
#pragma unroll
    for (int ct = 0; ct < 4; ct++)
#pragma unroll
      for (int r = 0; r < 4; r++) {
        int idx = ibase + 64 * ch + 16 * ct - r;
        dval[ct][r] = bs2f(Dl[(tl0 + r) * 40 + Ll[idx]]);
      }

    // ---- S phase: content logits (reads Kl) ----
    f32x4 Sacc[4];
    __builtin_amdgcn_s_setprio(1);
#pragma unroll
    for (int ct = 0; ct < 4; ct++) {
      Sacc[ct] = (f32x4){0.f, 0.f, 0.f, 0.f};
#pragma unroll
      for (int ks = 0; ks < 2; ks++) {
        short8 bfr = *(const short8*)(
            Kl + (16 * ct + ln) * 64 + ((quad + 4 * ks) ^ (ln & 7)) * 8);
        Sacc[ct] = __builtin_amdgcn_mfma_f32_16x16x32_bf16(qw8[ks], bfr, Sacc[ct], 0, 0, 0);
      }
    }
    __builtin_amdgcn_s_setprio(0);

    float pS[4][4];
#pragma unroll
    for (int ct = 0; ct < 4; ct++)
#pragma unroll
      for (int r = 0; r < 4; r++)
        pS[ct][r] = Sacc[ct][r] + dval[ct][r];

    // ---- softmax: DPP max-reduce + defer-max (THR=8), sum via ones-MFMA ----
    float mx[4];
#pragma unroll
    for (int r = 0; r < 4; r++) {
      float m2 = fmaxf(fmaxf(pS[0][r], pS[1][r]), fmaxf(pS[2][r], pS[3][r]));
      DPP_MAXSTEP(m2, 0xB1);    // quad_perm [1,0,3,2]  (xor 1)
      DPP_MAXSTEP(m2, 0x4E);    // quad_perm [2,3,0,1]  (xor 2)
      DPP_MAXSTEP(m2, 0x124);   // row_ror:4
      DPP_MAXSTEP(m2, 0x128);   // row_ror:8
      mx[r] = m2;
    }
    int need = (mx[0] > m_i[0] + 8.f) | (mx[1] > m_i[1] + 8.f) |
               (mx[2] > m_i[2] + 8.f) | (mx[3] > m_i[3] + 8.f);
    if (__any(need)) {
#pragma unroll
      for (int r = 0; r < 4; r++) {
        float mnew = fmaxf(m_i[r], mx[r]);
        float alpha = __expf(m_i[r] - mnew);
        m_i[r] = mnew;
        Lacc[r] *= alpha;
#pragma unroll
        for (int vt = 0; vt < 12; vt++) Oacc[vt][r] *= alpha;
      }
    }
#pragma unroll
    for (int ct = 0; ct < 4; ct++)
#pragma unroll
      for (int r = 0; r < 4; r++)
        pS[ct][r] = __expf(pS[ct][r] - m_i[r]);
    // probs -> Pp (bf16, per-wave scratch; same-wave RAW via lgkmcnt)
#pragma unroll
    for (int ct = 0; ct < 4; ct++)
#pragma unroll
      for (int r = 0; r < 4; r++)
        Pp[(4 * quad + r) * 72 + 16 * ct + ln] = f2bs(pS[ct][r]);
    __asm__ volatile("s_waitcnt lgkmcnt(0)" ::: "memory");
    short8 afr[2];
#pragma unroll
    for (int ks = 0; ks < 2; ks++)
      afr[ks] = *(const short8*)(Pp + ln * 72 + quad * 8 + ks * 32);

    __syncthreads();   // #1: Kl free (S done); V(ch) drained into LDS

    // ---- issue K(ch+1) DMA (covered by PV) ----
    if (ch < 11) {
      const int s0n = sk * 768 + ch * 64 + 64;
#pragma unroll
      for (int i = 0; i < 2; i++) {
        int kc = w * 2 + i, sr = kc * 8 + lr;
        gld_lds16(kb + (size_t)(bT + s0n + sr) * 512 + h * 64 + lcx * 8,
                  (ushort*)(smem + kc * 1024) + lane * 8);
      }
    }

    // ---- PV phase (reads Vl + afr; covers K(ch+1) DMA latency) ----
    __builtin_amdgcn_s_setprio(1);
    // l += sum(P) per row (every C column = row sum; read any ln)
    Lacc = __builtin_amdgcn_mfma_f32_16x16x32_bf16(afr[0], ones8, Lacc, 0, 0, 0);
    Lacc = __builtin_amdgcn_mfma_f32_16x16x32_bf16(afr[1], ones8, Lacc, 0, 0, 0);
#pragma unroll
    for (int vt = 0; vt < 12; vt++) {
#pragma unroll
      for (int ks = 0; ks < 2; ks++) {
        short8 bfr = *(const short8*)(
            Vl + (16 * vt + ln) * 64 + ((quad + 4 * ks) ^ (ln & 7)) * 8);
        Oacc[vt] = __builtin_amdgcn_mfma_f32_16x16x32_bf16(afr[ks], bfr, Oacc[vt], 0, 0, 0);
      }
    }
    __builtin_amdgcn_s_setprio(0);

    __syncthreads();   // #2: Vl free (PV done); K(ch+1) drained

    // ---- issue V(ch+1) DMA (covered by next S + gather + softmax) ----
    if (ch < 11) {
      const int s0n = sk * 768 + ch * 64 + 64;
#pragma unroll
      for (int i = 0; i < 6; i++) {
        int kc = w * 6 + i, vr = kc * 8 + lr;
        gld_lds16(vtb + (size_t)(h * 192 + vr) * 3072 + bT + s0n + lcx * 8,
                  (ushort*)(smem + 8192 + kc * 1024) + lane * 8);
      }
    }
  }

  // epilogue: normalized bf16 partial + (m,l);  l = Lacc (all cols equal)
  ushort* op = sk ? op1 : op0;
  float inv[4];
#pragma unroll
  for (int r = 0; r < 4; r++) inv[r] = 1.f / Lacc[r];
#pragma unroll
  for (int vt = 0; vt < 12; vt++)
#pragma unroll
    for (int r = 0; r < 4; r++) {
      int t = t0 + 16 * w + 4 * quad + r;
      op[(size_t)(bT + t) * 1536 + h * 192 + 16 * vt + ln] = f2bs(Oacc[vt][r] * inv[r]);
    }
  if (ln == 0) {
#pragma unroll
    for (int r = 0; r < 4; r++) {
      int t = t0 + 16 * w + 4 * quad + r;
      float2 v; v.x = m_i[r]; v.y = Lacc[r];
      mlb[((sk * 2 + b) * 8 + h) * 1536 + t] = v;
    }
  }
}

// ---------------------------------------------------------------------------
// Combine the two split-K partials: O = sum_i e^{m_i-M} l_i O_i / sum e^{m-M} l
// ---------------------------------------------------------------------------
__global__ __launch_bounds__(256) void attn_combine(
    const ushort* __restrict__ op0, const ushort* __restrict__ op1,
    const float2* __restrict__ mlb, ushort* __restrict__ att) {
  int g = blockIdx.x * 256 + threadIdx.x;   // group of 4 bf16
  int row = g / 384;                        // 0..3071
  int c4 = (g - row * 384) * 4;             // 0..1532
  int b = row >= 1536;
  int t = row - b * 1536;
  int h = c4 / 192;
  float2 ml0 = mlb[((0 + b) * 8 + h) * 1536 + t];
  float2 ml1 = mlb[((2 + b) * 8 + h) * 1536 + t];
  float M = fmaxf(ml0.x, ml1.x);
  float w0 = __expf(ml0.x - M) * ml0.y;
  float w1 = __expf(ml1.x - M) * ml1.y;
  float inv = 1.f / (w0 + w1);
  w0 *= inv; w1 *= inv;
  size_t off = (size_t)row * 1536 + c4;
  uint2 a = *(const uint2*)(op0 + off);
  uint2 c = *(const uint2*)(op1 + off);
  uint2 o;
  float r0 = w0 * bs2f((ushort)(a.x & 0xffff)) + w1 * bs2f((ushort)(c.x & 0xffff));
  float r1 = w0 * bs2f((ushort)(a.x >> 16))    + w1 * bs2f((ushort)(c.x >> 16));
  float r2 = w0 * bs2f((ushort)(a.y & 0xffff)) + w1 * bs2f((ushort)(c.y & 0xffff));
  float r3 = w0 * bs2f((ushort)(a.y >> 16))    + w1 * bs2f((ushort)(c.y >> 16));
  o.x = (uint)f2bs(r0) | ((uint)f2bs(r1) << 16);
  o.y = (uint)f2bs(r2) | ((uint)f2bs(r3) << 16);
  *(uint2*)(att + off) = o;
}

// ---------------------------------------------------------------------------
extern "C" void kernel_launch(void* const* d_in, const int* in_sizes, int n_in,
                              void* d_out, int out_size, void* d_ws, size_t ws_size,
                              hipStream_t stream) {
  const float* x   = (const float*)d_in[0];
  const float* Wq  = (const float*)d_in[1];
  const float* Wk  = (const float*)d_in[2];
  const float* Wv  = (const float*)d_in[3];
  const float* Wr  = (const float*)d_in[4];
  const float* rwb = (const float*)d_in[5];
  const float* rrb = (const float*)d_in[6];
  const float* Wo  = (const float*)d_in[7];
  const float* bo  = (const float*)d_in[8];
  float* out = (float*)d_out;

  char* ws = (char*)d_ws;
  // Region A [0, 9437184): xb (prep->qkv) -> op1 (attn) -> att (combine, same
  // addresses elementwise) -> gemm_out input.
  ushort* xb  = (ushort*)ws;
  ushort* op1 = (ushort*)ws;
  ushort* att = (ushort*)ws;
  ushort* Wot = (ushort*)(ws + 9437184);    // [1536][1536] bf16, until gemm_out
  ushort* Wt  = (ushort*)(ws + 14155776);   // [2560][1536] bf16, until gemm_qkv
  ushort* op0 = (ushort*)(ws + 14155776);   // overlays dead Wt (attn phase)
  ushort* qb  = (ushort*)(ws + 23592960);   // [3072][512] bf16 (scaled)
  ushort* kb  = (ushort*)(ws + 26738688);   // [3072][512] bf16
  ushort* vtb = (ushort*)(ws + 29884416);   // [1536][3072] bf16 (V^T)
  unsigned char* lutb = (unsigned char*)(ws + 41287680);  // [3072] u8
  ushort* rkdb = (ushort*)(ws + 41290752);  // [8][40][64] bf16 (40KB)
  float2* mlb = (float2*)(ws + 42467328);   // [2][2][8][1536] (m,l)

  prep<<<dim3(48, 48, 6), dim3(256), 0, stream>>>(
      x, Wq, Wk, Wv, Wo, Wr, xb, Wt, Wot, rkdb, lutb);
  gemm_qkv<<<dim3(20, 24), dim3(256), 0, stream>>>(xb, Wt, qb, kb, vtb);
  attn_mfma<<<dim3(24, 8, 4), dim3(256), 0, stream>>>(
      qb, kb, vtb, rkdb, lutb, rwb, rrb, op0, op1, mlb);
  attn_combine<<<dim3(4608), dim3(256), 0, stream>>>(op0, op1, mlb, att);
  gemm_out<<<dim3(12, 24), dim3(256), 0, stream>>>(att, Wot, bo, out);
}

// Round 14
// 208.783 us; speedup vs baseline: 1.0281x; 1.0114x over previous
//
#include <hip/hip_runtime.h>
#include <hip/hip_bf16.h>

typedef __hip_bfloat16 bf16;
typedef unsigned short ushort;
typedef unsigned int uint;
typedef __attribute__((ext_vector_type(8))) short short8;
typedef __attribute__((ext_vector_type(4))) float f32x4;

#define Bsz 2
#define Tn  1536
#define Cn  1536
#define Hn  8
#define Kn  64
#define Vn  192
// H*K = 512, H*V = 1536, 2T-1 = 3071

__device__ __forceinline__ ushort f2bs(float f) {
  union { bf16 h; ushort u; } cv;
  cv.h = __float2bfloat16(f);
  return cv.u;
}
__device__ __forceinline__ float bs2f(ushort u) {
  union { float f; uint v; } cv; cv.v = ((uint)u) << 16; return cv.f;
}

// async global->LDS, 16B per lane; LDS dest = wave-uniform base + lane*16
__device__ __forceinline__ void gld_lds16(const ushort* g, ushort* l) {
  __builtin_amdgcn_global_load_lds(
      (const __attribute__((address_space(1))) uint*)g,
      (__attribute__((address_space(3))) uint*)l, 16, 0, 0);
}

// 16-lane max-reduce step via DPP (VALU-rate, no LDS): x = max(x, dpp(x))
#define DPP_MAXSTEP(x, ctrl)                                                  \
  do {                                                                        \
    union { float f; int i; } a_, b_;                                         \
    a_.f = (x);                                                               \
    b_.i = __builtin_amdgcn_update_dpp(a_.i, a_.i, (ctrl), 0xf, 0xf, true);   \
    (x) = fmaxf((x), b_.f);                                                   \
  } while (0)

// ---------------------------------------------------------------------------
// Merged prep kernel, grid (48,48,6):
//  z=0..3: transpose+cvt  W{q,k,v,o} f32 [1536][Cc] -> bf16 [Cc][1536]
//  z=4   : x f32 -> xb bf16 (vectorized x4, grid-stride)
//  z=5   : rkd[8][40][64] bf16 (33 DISTINCT rel-basis rows per head; rows
//          33..39 ZERO pad) and lutb[3072] u8: d+1535 -> row index u.
// ---------------------------------------------------------------------------
__global__ __launch_bounds__(256) void prep(
    const float* __restrict__ x,  const float* __restrict__ Wq,
    const float* __restrict__ Wk, const float* __restrict__ Wv,
    const float* __restrict__ Wo, const float* __restrict__ Wr,
    ushort* __restrict__ xb, ushort* __restrict__ Wt,
    ushort* __restrict__ Wot, ushort* __restrict__ rkdb,
    unsigned char* __restrict__ lutb) {
  const int z = blockIdx.z;
  if (z < 4) {
    if (z < 2 && blockIdx.x >= 16) return;
    const float* in = (z == 0) ? Wq : (z == 1) ? Wk : (z == 2) ? Wv : Wo;
    ushort* out = (z == 0) ? Wt : (z == 1) ? Wt + 512 * 1536
                : (z == 2) ? Wt + 1024 * 1536 : Wot;
    const int Cc = (z < 2) ? 512 : 1536;
    __shared__ float tile[32][33];
    const int bx = blockIdx.x * 32;
    const int by = blockIdx.y * 32;
    const int tx = threadIdx.x & 31, ty = threadIdx.x >> 5;
#pragma unroll
    for (int i = 0; i < 32; i += 8)
      tile[ty + i][tx] = in[(size_t)(by + ty + i) * Cc + bx + tx];
    __syncthreads();
#pragma unroll
    for (int i = 0; i < 32; i += 8)
      out[(size_t)(bx + ty + i) * 1536 + by + tx] = f2bs(tile[tx][ty + i]);
  } else if (z == 4) {
    const int n4 = 3072 * 1536 / 4;
    for (int i = (blockIdx.y * 48 + blockIdx.x) * 256 + threadIdx.x; i < n4;
         i += 2304 * 256) {
      float4 v = ((const float4*)x)[i];
      uint2 o;
      o.x = (uint)f2bs(v.x) | ((uint)f2bs(v.y) << 16);
      o.y = (uint)f2bs(v.z) | ((uint)f2bs(v.w) << 16);
      ((uint2*)xb)[i] = o;
    }
  } else {
    const int base = (blockIdx.y * 48 + blockIdx.x) * 256 + threadIdx.x;
    if (base < 8 * 40 * 64) {
      // rkd entry: h, u-row (pad 33..39 = 0), k
      const int h = base / 2560, rem = base % 2560, u = rem >> 6, k = rem & 63;
      float acc = 0.f;
      if (u < 33) {
        const float sg = (u == 32) ? 0.f : (u < 16 ? 1.f : -1.f);
        const int c = (u == 32) ? 16 : (u < 16 ? u + 1 : u - 15);
        // active features are the c LARGEST widths: i = 16-c .. 15 (ascending,
        // same summation order as the original rkb builder)
#pragma unroll
        for (int i = 0; i < 16; i++)
          if (i >= 16 - c)
            acc += Wr[i * 512 + h * 64 + k] + sg * Wr[(16 + i) * 512 + h * 64 + k];
      }
      rkdb[h * 2560 + u * 64 + k] = f2bs(acc);
    } else if (base < 8 * 40 * 64 + 3072) {
      const int idx = base - 8 * 40 * 64;       // 0..3071 (3071 = pad)
      const int d = idx - 1535;
      const float ad = fabsf((float)d);
      int c = 0;
#pragma unroll
      for (int i = 0; i < 16; i++) {
        double cw = exp(log((double)(Tn + 1)) * (double)(i + 1) / 16.0) - 1.0;
        if ((float)cw > ad) c++;
      }
      lutb[idx] = (unsigned char)((d == 0) ? 32 : (d > 0 ? c - 1 : 15 + c));
    }
  }
}

// ---------------------------------------------------------------------------
// v9 GEMM core: 128x128 tile, BK=64, DOUBLE-BUFFERED LDS (T3-minimum 2-phase:
// issue next-tile DMA -> compute current -> one barrier/iter; drain covered).
// 128B rows would be a 16-way ds_read conflict -> attn-style XOR swizzle (T2):
// global 16B chunk c of row r staged at physical chunk c^(r&7); ds_read col
// chunk (quad+4ks)^(ln&7). LDS 64KB (2 blocks/CU cap; grids are ~1-2/CU).
// STAGE64: one [128r x 64k] bf16 tile = 16 chunks of 1KB; 4 per wave.
// ---------------------------------------------------------------------------
#define STAGE64(src, base_row, kk, dst)                                       \
  _Pragma("unroll")                                                           \
  for (int i_ = 0; i_ < 4; i_++) {                                            \
    int kc_ = w * 4 + i_, sr_ = kc_ * 8 + lr;                                 \
    gld_lds16(src + (size_t)(base_row + sr_) * 1536 + (kk) + lcx * 8,         \
              dst + kc_ * 512 + lane * 8);                                    \
  }

// ---------------------------------------------------------------------------
// Fused QKV MFMA GEMM: xb @ Wt^T-layout -> qb/kb/vtb.
// XCD-chunked block swizzle (grid 480 = 8 x 60).
// ---------------------------------------------------------------------------
__global__ __launch_bounds__(256) void gemm_qkv(
    const ushort* __restrict__ xb, const ushort* __restrict__ Wt,
    ushort* __restrict__ qb, ushort* __restrict__ kb, ushort* __restrict__ vtb) {
  __shared__ ushort Al[2][128 * 64];
  __shared__ ushort Bl[2][128 * 64];
  const int tid = threadIdx.x;
  const int w = tid >> 6, lane = tid & 63, quad = lane >> 4, ln = lane & 15;
  const int lr = lane >> 3, lcx = (lane & 7) ^ lr;
  const int Lb = blockIdx.x + 20 * blockIdx.y;          // 0..479
  const int wg = (Lb & 7) * 60 + (Lb >> 3);             // bijective (480%8==0)
  const int bm = (wg % 24) * 128, bn = (wg / 24) * 128;
  const int wm = (w & 1) * 64, wn = (w >> 1) * 64;
  f32x4 acc[4][4];
#pragma unroll
  for (int i = 0; i < 4; i++)
#pragma unroll
    for (int j = 0; j < 4; j++) acc[i][j] = (f32x4){0.f, 0.f, 0.f, 0.f};

  STAGE64(xb, bm, 0, Al[0]);
  STAGE64(Wt, bn, 0, Bl[0]);
  __syncthreads();

  int cur = 0;
  for (int k0 = 0; k0 < 1536; k0 += 64) {
    if (k0 + 64 < 1536) {
      STAGE64(xb, bm, k0 + 64, Al[cur ^ 1]);
      STAGE64(Wt, bn, k0 + 64, Bl[cur ^ 1]);
    }
#pragma unroll
    for (int ks = 0; ks < 2; ks++) {
      short8 af[4], bfr[4];
#pragma unroll
      for (int t = 0; t < 4; t++) {
        int cx = ((quad + 4 * ks) ^ (ln & 7)) * 8;
        af[t]  = *(const short8*)(Al[cur] + (wm + t * 16 + ln) * 64 + cx);
        bfr[t] = *(const short8*)(Bl[cur] + (wn + t * 16 + ln) * 64 + cx);
      }
#pragma unroll
      for (int mt = 0; mt < 4; mt++)
#pragma unroll
        for (int nt = 0; nt < 4; nt++)
          acc[mt][nt] = __builtin_amdgcn_mfma_f32_16x16x32_bf16(
              af[mt], bfr[nt], acc[mt][nt], 0, 0, 0);
    }
    __syncthreads();   // reads of cur done; DMA for cur^1 drained
    cur ^= 1;
  }

  if (bn < 512) {
#pragma unroll
    for (int mt = 0; mt < 4; mt++)
#pragma unroll
      for (int nt = 0; nt < 4; nt++)
#pragma unroll
        for (int r = 0; r < 4; r++) {
          int m = bm + wm + mt * 16 + quad * 4 + r;
          int n = bn + wn + nt * 16 + ln;
          qb[(size_t)m * 512 + n] = f2bs(acc[mt][nt][r] * 0.125f);
        }
  } else if (bn < 1024) {
#pragma unroll
    for (int mt = 0; mt < 4; mt++)
#pragma unroll
      for (int nt = 0; nt < 4; nt++)
#pragma unroll
        for (int r = 0; r < 4; r++) {
          int m = bm + wm + mt * 16 + quad * 4 + r;
          int n = bn - 512 + wn + nt * 16 + ln;
          kb[(size_t)m * 512 + n] = f2bs(acc[mt][nt][r]);
        }
  } else {
#pragma unroll
    for (int mt = 0; mt < 4; mt++)
#pragma unroll
      for (int nt = 0; nt < 4; nt++) {
        int vcol = bn - 1024 + wn + nt * 16 + ln;
        int m0 = bm + wm + mt * 16 + quad * 4;
        uint2 val;
        val.x = (uint)f2bs(acc[mt][nt][0]) | ((uint)f2bs(acc[mt][nt][1]) << 16);
        val.y = (uint)f2bs(acc[mt][nt][2]) | ((uint)f2bs(acc[mt][nt][3]) << 16);
        *(uint2*)(vtb + (size_t)vcol * 3072 + m0) = val;
      }
  }
}

// ---------------------------------------------------------------------------
// Output MFMA GEMM: att(bf16) @ Wot + bo -> f32 out.  Same v9 core.
// XCD-chunked swizzle (grid 288 = 8 x 36).
// ---------------------------------------------------------------------------
__global__ __launch_bounds__(256) void gemm_out(
    const ushort* __restrict__ att, const ushort* __restrict__ Wot,
    const float* __restrict__ bo, float* __restrict__ out) {
  __shared__ ushort Al[2][128 * 64];
  __shared__ ushort Bl[2][128 * 64];
  const int tid = threadIdx.x;
  const int w = tid >> 6, lane = tid & 63, quad = lane >> 4, ln = lane & 15;
  const int lr = lane >> 3, lcx = (lane & 7) ^ lr;
  const int Lb = blockIdx.x + 12 * blockIdx.y;          // 0..287
  const int wg = (Lb & 7) * 36 + (Lb >> 3);             // bijective (288%8==0)
  const int bm = (wg % 24) * 128, bn = (wg / 24) * 128;
  const int wm = (w & 1) * 64, wn = (w >> 1) * 64;
  f32x4 acc[4][4];
#pragma unroll
  for (int i = 0; i < 4; i++)
#pragma unroll
    for (int j = 0; j < 4; j++) acc[i][j] = (f32x4){0.f, 0.f, 0.f, 0.f};

  STAGE64(att, bm, 0, Al[0]);
  STAGE64(Wot, bn, 0, Bl[0]);
  __syncthreads();

  int cur = 0;
  for (int k0 = 0; k0 < 1536; k0 += 64) {
    if (k0 + 64 < 1536) {
      STAGE64(att, bm, k0 + 64, Al[cur ^ 1]);
      STAGE64(Wot, bn, k0 + 64, Bl[cur ^ 1]);
    }
#pragma unroll
    for (int ks = 0; ks < 2; ks++) {
      short8 af[4], bfr[4];
#pragma unroll
      for (int t = 0; t < 4; t++) {
        int cx = ((quad + 4 * ks) ^ (ln & 7)) * 8;
        af[t]  = *(const short8*)(Al[cur] + (wm + t * 16 + ln) * 64 + cx);
        bfr[t] = *(const short8*)(Bl[cur] + (wn + t * 16 + ln) * 64 + cx);
      }
#pragma unroll
      for (int mt = 0; mt < 4; mt++)
#pragma unroll
        for (int nt = 0; nt < 4; nt++)
          acc[mt][nt] = __builtin_amdgcn_mfma_f32_16x16x32_bf16(
              af[mt], bfr[nt], acc[mt][nt], 0, 0, 0);
    }
    __syncthreads();
    cur ^= 1;
  }
#pragma unroll
  for (int mt = 0; mt < 4; mt++)
#pragma unroll
    for (int nt = 0; nt < 4; nt++)
#pragma unroll
      for (int r = 0; r < 4; r++) {
        int m = bm + wm + mt * 16 + quad * 4 + r;
        int n = bn + wn + nt * 16 + ln;
        out[(size_t)m * 1536 + n] = acc[mt][nt][r] + bo[n];
      }
}

// ---------------------------------------------------------------------------
// MFMA flash attention, split-K(x2), t-tile 64, 4 waves, DMA staging.
// XCD-AWARE SWIZZLE: linear block id L -> xcd = L&7 owns head h = xcd only.
// FINAL configuration (best measured: attn ~46.0us, total ~211.0us).
// Techniques: rel-path eliminated via 33-row D-table + LUT (central-mask
// basis is a step fn of |d|); D-table built in-prologue with 6 MFMAs;
// DPP max-reduce + ones-MFMA row-sum + defer-max (THR=8) softmax;
// 2-barrier covered-drain K/V pipeline; XOR-swizzled DMA staging.
// Schedule:
//   gather (Dl/Ll) -> S MFMAs on Kl -> softmax(DPP, defer-max) -> Pp/afr
//   bar#1 (drains V(ch); Kl free) -> issue K(ch+1)
//   PV+Lacc MFMAs on Vl (covers K DMA)
//   bar#2 (drains K(ch+1); Vl free) -> issue V(ch+1)
// LDS [50176B]: K[64]x128B @0, V[192]x128B @8192, D[64][40]bf16 @32768,
//   LUT[3072]u8 @37888, per-wave Pp bf16[16][72] @40960.  3 blocks/CU.
// XOR swizzle (K/V): 16B chunk c of row r stored at physical chunk c^(r&7).
// ---------------------------------------------------------------------------
__global__ __launch_bounds__(256, 3) void attn_mfma(
    const ushort* __restrict__ qb, const ushort* __restrict__ kb,
    const ushort* __restrict__ vtb, const ushort* __restrict__ rkdb,
    const unsigned char* __restrict__ lutb,
    const float* __restrict__ rwb, const float* __restrict__ rrb,
    ushort* __restrict__ op0, ushort* __restrict__ op1,
    float2* __restrict__ mlb) {
  __shared__ __align__(16) char smem[50176];
  ushort* Kl = (ushort*)smem;                        // [64] rows x 128B
  ushort* Vl = (ushort*)(smem + 8192);               // [192] rows x 128B
  ushort* Dl = (ushort*)(smem + 32768);              // [64][40] bf16
  unsigned char* Ll = (unsigned char*)(smem + 37888);// [3072] u8

  const int L  = blockIdx.x + 24 * blockIdx.y + 192 * blockIdx.z;
  const int h  = L & 7;                     // XCD id under round-robin
  const int g  = L >> 3;
  const int bsk = g / 24;
  const int b  = bsk >> 1;
  const int sk = bsk & 1;
  const int t0 = (g - bsk * 24) * 64;
  const int bT = b * Tn;
  const int tid = threadIdx.x;
  const int w = tid >> 6, lane = tid & 63, quad = lane >> 4, ln = lane & 15;

  ushort* Pp = (ushort*)(smem + 40960 + w * 2304);   // [16][72] bf16 per wave

  const int lr  = lane >> 3;          // staging: row-in-chunk 0..7
  const int lcx = (lane & 7) ^ lr;    // staging: logical 16B chunk (swizzle)

  // ---- prologue staging: K(0), V(0), LUT ----
  {
    const int s0 = sk * 768;
#pragma unroll
    for (int i = 0; i < 2; i++) {
      int kc = w * 2 + i, sr = kc * 8 + lr;
      gld_lds16(kb + (size_t)(bT + s0 + sr) * 512 + h * 64 + lcx * 8,
                (ushort*)(smem + kc * 1024) + lane * 8);
    }
#pragma unroll
    for (int i = 0; i < 6; i++) {
      int kc = w * 6 + i, vr = kc * 8 + lr;
      gld_lds16(vtb + (size_t)(h * 192 + vr) * 3072 + bT + s0 + lcx * 8,
                (ushort*)(smem + 8192 + kc * 1024) + lane * 8);
    }
    if (w < 3)
      gld_lds16((const ushort*)(lutb + w * 1024) + lane * 8,
                (ushort*)(smem + 37888 + w * 1024) + lane * 8);
  }

  // Q fragments (A-layout m=ln, k=quad*8+ks*32+e): content bias + rel bias
  short8 qw8[2], qr8[2];
  {
    const ushort* qrow = qb + (size_t)(bT + t0 + 16 * w + ln) * 512 + h * 64;
#pragma unroll
    for (int ks = 0; ks < 2; ks++) {
      int k0 = quad * 8 + ks * 32;
#pragma unroll
      for (int e = 0; e < 8; e++) {
        float qv = bs2f(qrow[k0 + e]);
        qw8[ks][e] = (short)f2bs(qv + rwb[h * 64 + k0 + e]);
        qr8[ks][e] = (short)f2bs(qv + rrb[h * 64 + k0 + e]);
      }
    }
  }

  // ---- D table via MFMA: D[t][u] = (q+rrb) . rkd[h][u], u<33 (pad rows=0) --
  {
    f32x4 Dacc[3];
#pragma unroll
    for (int ut = 0; ut < 3; ut++) {
      Dacc[ut] = (f32x4){0.f, 0.f, 0.f, 0.f};
#pragma unroll
      for (int ks = 0; ks < 2; ks++) {
        int urow = 16 * ut + ln; urow = urow > 39 ? 39 : urow;  // rows>=33 are 0
        short8 bfr = *(const short8*)(rkdb + h * 2560 + urow * 64 + quad * 8 + ks * 32);
        Dacc[ut] = __builtin_amdgcn_mfma_f32_16x16x32_bf16(qr8[ks], bfr, Dacc[ut], 0, 0, 0);
      }
    }
    const int trow = 16 * w + 4 * quad;   // wave-local t rows (C: m=4*quad+r)
#pragma unroll
    for (int ut = 0; ut < 2; ut++)
#pragma unroll
      for (int r = 0; r < 4; r++)
        Dl[(trow + r) * 40 + 16 * ut + ln] = f2bs(Dacc[ut][r]);
    if (ln == 0) {
#pragma unroll
      for (int r = 0; r < 4; r++)
        Dl[(trow + r) * 40 + 32] = f2bs(Dacc[2][r]);
    }
  }

  f32x4 Oacc[12];
  f32x4 Lacc = (f32x4){0.f, 0.f, 0.f, 0.f};   // online l via ones-MFMA
  float m_i[4];
#pragma unroll
  for (int vt = 0; vt < 12; vt++) Oacc[vt] = (f32x4){0.f, 0.f, 0.f, 0.f};
#pragma unroll
  for (int r = 0; r < 4; r++) m_i[r] = -1e30f;

  short8 ones8;
#pragma unroll
  for (int e = 0; e < 8; e++) ones8[e] = (short)0x3F80;   // bf16 1.0

  __syncthreads();   // K(0)/V(0)/LUT staged; Dl writes visible

  const int ibase = sk * 768 - t0 - 16 * w - 4 * quad + ln + 1535;
  const int tl0 = 16 * w + 4 * quad;

  for (int ch = 0; ch < 12; ch++) {
    // ---- rel lookups (Dl/Ll static; independent of S MFMAs) ----
    float dval[4][4];
#pragma unroll
    for (int ct = 0; ct < 4; ct++)
#pragma unroll
      for (int r = 0; r < 4; r++) {
        int idx = ibase + 64 * ch + 16 * ct - r;
        dval[ct][r] = bs2f(Dl[(tl0 + r) * 40 + Ll[idx]]);
      }

    // ---- S phase: content logits (reads Kl) ----
    f32x4 Sacc[4];
    __builtin_amdgcn_s_setprio(1);
#pragma unroll
    for (int ct = 0; ct < 4; ct++) {
      Sacc[ct] = (f32x4){0.f, 0.f, 0.f, 0.f};
#pragma unroll
      for (int ks = 0; ks < 2; ks++) {
        short8 bfr = *(const short8*)(
            Kl + (16 * ct + ln) * 64 + ((quad + 4 * ks) ^ (ln & 7)) * 8);
        Sacc[ct] = __builtin_amdgcn_mfma_f32_16x16x32_bf16(qw8[ks], bfr, Sacc[ct], 0, 0, 0);
      }
    }
    __builtin_amdgcn_s_setprio(0);

    float pS[4][4];
#pragma unroll
    for (int ct = 0; ct < 4; ct++)
#pragma unroll
      for (int r = 0; r < 4; r++)
        pS[ct][r] = Sacc[ct][r] + dval[ct][r];

    // ---- softmax: DPP max-reduce + defer-max (THR=8), sum via ones-MFMA ----
    float mx[4];
#pragma unroll
    for (int r = 0; r < 4; r++) {
      float m2 = fmaxf(fmaxf(pS[0][r], pS[1][r]), fmaxf(pS[2][r], pS[3][r]));
      DPP_MAXSTEP(m2, 0xB1);    // quad_perm [1,0,3,2]  (xor 1)
      DPP_MAXSTEP(m2, 0x4E);    // quad_perm [2,3,0,1]  (xor 2)
      DPP_MAXSTEP(m2, 0x124);   // row_ror:4
      DPP_MAXSTEP(m2, 0x128);   // row_ror:8
      mx[r] = m2;
    }
    int need = (mx[0] > m_i[0] + 8.f) | (mx[1] > m_i[1] + 8.f) |
               (mx[2] > m_i[2] + 8.f) | (mx[3] > m_i[3] + 8.f);
    if (__any(need)) {
#pragma unroll
      for (int r = 0; r < 4; r++) {
        float mnew = fmaxf(m_i[r], mx[r]);
        float alpha = __expf(m_i[r] - mnew);
        m_i[r] = mnew;
        Lacc[r] *= alpha;
#pragma unroll
        for (int vt = 0; vt < 12; vt++) Oacc[vt][r] *= alpha;
      }
    }
#pragma unroll
    for (int ct = 0; ct < 4; ct++)
#pragma unroll
      for (int r = 0; r < 4; r++)
        pS[ct][r] = __expf(pS[ct][r] - m_i[r]);
    // probs -> Pp (bf16, per-wave scratch; same-wave RAW via lgkmcnt)
#pragma unroll
    for (int ct = 0; ct < 4; ct++)
#pragma unroll
      for (int r = 0; r < 4; r++)
        Pp[(4 * quad + r) * 72 + 16 * ct + ln] = f2bs(pS[ct][r]);
    __asm__ volatile("s_waitcnt lgkmcnt(0)" ::: "memory");
    short8 afr[2];
#pragma unroll
    for (int ks = 0; ks < 2; ks++)
      afr[ks] = *(const short8*)(Pp + ln * 72 + quad * 8 + ks * 32);

    __syncthreads();   // #1: Kl free (S done); V(ch) drained into LDS

    // ---- issue K(ch+1) DMA (covered by PV) ----
    if (ch < 11) {
      const int s0n = sk * 768 + ch * 64 + 64;
#pragma unroll
      for (int i = 0; i < 2; i++) {
        int kc = w * 2 + i, sr = kc * 8 + lr;
        gld_lds16(kb + (size_t)(bT + s0n + sr) * 512 + h * 64 + lcx * 8,
                  (ushort*)(smem + kc * 1024) + lane * 8);
      }
    }

    // ---- PV phase (reads Vl + afr; covers K(ch+1) DMA latency) ----
    __builtin_amdgcn_s_setprio(1);
    // l += sum(P) per row (every C column = row sum; read any ln)
    Lacc = __builtin_amdgcn_mfma_f32_16x16x32_bf16(afr[0], ones8, Lacc, 0, 0, 0);
    Lacc = __builtin_amdgcn_mfma_f32_16x16x32_bf16(afr[1], ones8, Lacc, 0, 0, 0);
#pragma unroll
    for (int vt = 0; vt < 12; vt++) {
#pragma unroll
      for (int ks = 0; ks < 2; ks++) {
        short8 bfr = *(const short8*)(
            Vl + (16 * vt + ln) * 64 + ((quad + 4 * ks) ^ (ln & 7)) * 8);
        Oacc[vt] = __builtin_amdgcn_mfma_f32_16x16x32_bf16(afr[ks], bfr, Oacc[vt], 0, 0, 0);
      }
    }
    __builtin_amdgcn_s_setprio(0);

    __syncthreads();   // #2: Vl free (PV done); K(ch+1) drained

    // ---- issue V(ch+1) DMA (covered by next S + gather + softmax) ----
    if (ch < 11) {
      const int s0n = sk * 768 + ch * 64 + 64;
#pragma unroll
      for (int i = 0; i < 6; i++) {
        int kc = w * 6 + i, vr = kc * 8 + lr;
        gld_lds16(vtb + (size_t)(h * 192 + vr) * 3072 + bT + s0n + lcx * 8,
                  (ushort*)(smem + 8192 + kc * 1024) + lane * 8);
      }
    }
  }

  // epilogue: normalized bf16 partial + (m,l);  l = Lacc (all cols equal)
  ushort* op = sk ? op1 : op0;
  float inv[4];
#pragma unroll
  for (int r = 0; r < 4; r++) inv[r] = 1.f / Lacc[r];
#pragma unroll
  for (int vt = 0; vt < 12; vt++)
#pragma unroll
    for (int r = 0; r < 4; r++) {
      int t = t0 + 16 * w + 4 * quad + r;
      op[(size_t)(bT + t) * 1536 + h * 192 + 16 * vt + ln] = f2bs(Oacc[vt][r] * inv[r]);
    }
  if (ln == 0) {
#pragma unroll
    for (int r = 0; r < 4; r++) {
      int t = t0 + 16 * w + 4 * quad + r;
      float2 v; v.x = m_i[r]; v.y = Lacc[r];
      mlb[((sk * 2 + b) * 8 + h) * 1536 + t] = v;
    }
  }
}

// ---------------------------------------------------------------------------
// Combine the two split-K partials: O = sum_i e^{m_i-M} l_i O_i / sum e^{m-M} l
// ---------------------------------------------------------------------------
__global__ __launch_bounds__(256) void attn_combine(
    const ushort* __restrict__ op0, const ushort* __restrict__ op1,
    const float2* __restrict__ mlb, ushort* __restrict__ att) {
  int g = blockIdx.x * 256 + threadIdx.x;   // group of 4 bf16
  int row = g / 384;                        // 0..3071
  int c4 = (g - row * 384) * 4;             // 0..1532
  int b = row >= 1536;
  int t = row - b * 1536;
  int h = c4 / 192;
  float2 ml0 = mlb[((0 + b) * 8 + h) * 1536 + t];
  float2 ml1 = mlb[((2 + b) * 8 + h) * 1536 + t];
  float M = fmaxf(ml0.x, ml1.x);
  float w0 = __expf(ml0.x - M) * ml0.y;
  float w1 = __expf(ml1.x - M) * ml1.y;
  float inv = 1.f / (w0 + w1);
  w0 *= inv; w1 *= inv;
  size_t off = (size_t)row * 1536 + c4;
  uint2 a = *(const uint2*)(op0 + off);
  uint2 c = *(const uint2*)(op1 + off);
  uint2 o;
  float r0 = w0 * bs2f((ushort)(a.x & 0xffff)) + w1 * bs2f((ushort)(c.x & 0xffff));
  float r1 = w0 * bs2f((ushort)(a.x >> 16))    + w1 * bs2f((ushort)(c.x >> 16));
  float r2 = w0 * bs2f((ushort)(a.y & 0xffff)) + w1 * bs2f((ushort)(c.y & 0xffff));
  float r3 = w0 * bs2f((ushort)(a.y >> 16))    + w1 * bs2f((ushort)(c.y >> 16));
  o.x = (uint)f2bs(r0) | ((uint)f2bs(r1) << 16);
  o.y = (uint)f2bs(r2) | ((uint)f2bs(r3) << 16);
  *(uint2*)(att + off) = o;
}

// ---------------------------------------------------------------------------
extern "C" void kernel_launch(void* const* d_in, const int* in_sizes, int n_in,
                              void* d_out, int out_size, void* d_ws, size_t ws_size,
                              hipStream_t stream) {
  const float* x   = (const float*)d_in[0];
  const float* Wq  = (const float*)d_in[1];
  const float* Wk  = (const float*)d_in[2];
  const float* Wv  = (const float*)d_in[3];
  const float* Wr  = (const float*)d_in[4];
  const float* rwb = (const float*)d_in[5];
  const float* rrb = (const float*)d_in[6];
  const float* Wo  = (const float*)d_in[7];
  const float* bo  = (const float*)d_in[8];
  float* out = (float*)d_out;

  char* ws = (char*)d_ws;
  // Region A [0, 9437184): xb (prep->qkv) -> op1 (attn) -> att (combine, same
  // addresses elementwise) -> gemm_out input.
  ushort* xb  = (ushort*)ws;
  ushort* op1 = (ushort*)ws;
  ushort* att = (ushort*)ws;
  ushort* Wot = (ushort*)(ws + 9437184);    // [1536][1536] bf16, until gemm_out
  ushort* Wt  = (ushort*)(ws + 14155776);   // [2560][1536] bf16, until gemm_qkv
  ushort* op0 = (ushort*)(ws + 14155776);   // overlays dead Wt (attn phase)
  ushort* qb  = (ushort*)(ws + 23592960);   // [3072][512] bf16 (scaled)
  ushort* kb  = (ushort*)(ws + 26738688);   // [3072][512] bf16
  ushort* vtb = (ushort*)(ws + 29884416);   // [1536][3072] bf16 (V^T)
  unsigned char* lutb = (unsigned char*)(ws + 41287680);  // [3072] u8
  ushort* rkdb = (ushort*)(ws + 41290752);  // [8][40][64] bf16 (40KB)
  float2* mlb = (float2*)(ws + 42467328);   // [2][2][8][1536] (m,l)

  prep<<<dim3(48, 48, 6), dim3(256), 0, stream>>>(
      x, Wq, Wk, Wv, Wo, Wr, xb, Wt, Wot, rkdb, lutb);
  gemm_qkv<<<dim3(20, 24), dim3(256), 0, stream>>>(xb, Wt, qb, kb, vtb);
  attn_mfma<<<dim3(24, 8, 4), dim3(256), 0, stream>>>(
      qb, kb, vtb, rkdb, lutb, rwb, rrb, op0, op1, mlb);
  attn_combine<<<dim3(4608), dim3(256), 0, stream>>>(op0, op1, mlb, att);
  gemm_out<<<dim3(12, 24), dim3(256), 0, stream>>>(att, Wot, bo, out);
}